// Round 1
// baseline (810.163 us; speedup 1.0000x reference)
//
#include <hip/hip_runtime.h>

#define NN 100000
#define NE 1600000
#define D 64

// ---------------- kernels ----------------

__global__ void deg_kernel(const int* __restrict__ col, int* __restrict__ deg) {
    int e = blockIdx.x * blockDim.x + threadIdx.x;
    if (e < NE) atomicAdd(&deg[col[e]], 1);
}

__global__ void dis_kernel(const int* __restrict__ deg, float* __restrict__ dis) {
    int i = blockIdx.x * blockDim.x + threadIdx.x;
    if (i < NN) dis[i] = rsqrtf((float)(deg[i] + 1)); // +1 self loop; always > 0
}

__global__ void softmax_kernel(const float* __restrict__ hw, float* __restrict__ wsm) {
    // 3 hop weights -> softmax, single thread
    float m = fmaxf(fmaxf(hw[0], hw[1]), hw[2]);
    float e0 = expf(hw[0] - m), e1 = expf(hw[1] - m), e2 = expf(hw[2] - m);
    float s = e0 + e1 + e2;
    wsm[0] = e0 / s; wsm[1] = e1 / s; wsm[2] = e2 / s;
}

// Fused: out (+)= wsm[wk] * cur ; nxt = dis[node]^2 * cur  (self-loop init)
__global__ void fuse_kernel(const float4* __restrict__ cur,
                            const float* __restrict__ dis,
                            const float* __restrict__ wsm, int wk,
                            float4* __restrict__ out,
                            float4* __restrict__ nxt,
                            int init_out, int write_nxt) {
    int idx = blockIdx.x * blockDim.x + threadIdx.x; // over NN*D/4
    if (idx >= NN * (D / 4)) return;
    int node = idx / (D / 4);
    float4 c = cur[idx];
    float w = wsm[wk];
    float4 o;
    if (init_out) {
        o.x = w * c.x; o.y = w * c.y; o.z = w * c.z; o.w = w * c.w;
    } else {
        o = out[idx];
        o.x += w * c.x; o.y += w * c.y; o.z += w * c.z; o.w += w * c.w;
    }
    out[idx] = o;
    if (write_nxt) {
        float di = dis[node];
        float d2 = di * di;
        float4 n;
        n.x = d2 * c.x; n.y = d2 * c.y; n.z = d2 * c.z; n.w = d2 * c.w;
        nxt[idx] = n;
    }
}

// One 64-lane wave per edge: lane d handles feature d.
__global__ void edge_kernel(const int* __restrict__ row, const int* __restrict__ col,
                            const float* __restrict__ dis,
                            const float* __restrict__ cur, float* __restrict__ nxt) {
    int t = blockIdx.x * blockDim.x + threadIdx.x;
    int e = t >> 6;
    int d = t & 63;
    if (e >= NE) return;
    int r = row[e];
    int c = col[e];
    float w = dis[r] * dis[c];
    atomicAdd(&nxt[r * D + d], cur[c * D + d] * w);
}

// ---------------- launch ----------------

extern "C" void kernel_launch(void* const* d_in, const int* in_sizes, int n_in,
                              void* d_out, int out_size, void* d_ws, size_t ws_size,
                              hipStream_t stream) {
    const float* x   = (const float*)d_in[0];
    const int*   ei  = (const int*)d_in[1];     // [2, NE] int32
    const float* hw  = (const float*)d_in[2];   // [3]
    float*       out = (float*)d_out;

    const int* row = ei;        // edge_index[0] -> scatter destination
    const int* col = ei + NE;   // edge_index[1] -> gather source

    char* ws = (char*)d_ws;
    size_t off = 0;
    auto alloc = [&](size_t bytes) { size_t p = off; off += (bytes + 255) & ~(size_t)255; return p; };
    float* wsm  = (float*)(ws + alloc(16));
    int*   deg  = (int*)  (ws + alloc((size_t)NN * 4));
    float* dis  = (float*)(ws + alloc((size_t)NN * 4));
    float* bufA = (float*)(ws + alloc((size_t)NN * D * 4));
    float* bufB = (float*)(ws + alloc((size_t)NN * D * 4));

    hipMemsetAsync(deg, 0, (size_t)NN * 4, stream);

    deg_kernel<<<(NE + 255) / 256, 256, 0, stream>>>(col, deg);
    dis_kernel<<<(NN + 255) / 256, 256, 0, stream>>>(deg, dis);
    softmax_kernel<<<1, 1, 0, stream>>>(hw, wsm);

    const int fuse_blocks = (NN * (D / 4) + 255) / 256;      // 6250
    const int edge_blocks = (NE * 64 + 255) / 256;           // 400000

    // hop 1: out = w0*x ; bufA = dis^2*x (self loop) ; edges: bufA += norm * x[col]
    fuse_kernel<<<fuse_blocks, 256, 0, stream>>>((const float4*)x, dis, wsm, 0,
                                                 (float4*)out, (float4*)bufA, 1, 1);
    edge_kernel<<<edge_blocks, 256, 0, stream>>>(row, col, dis, x, bufA);

    // hop 2: out += w1*bufA ; bufB = dis^2*bufA ; edges: bufB += norm * bufA[col]
    fuse_kernel<<<fuse_blocks, 256, 0, stream>>>((const float4*)bufA, dis, wsm, 1,
                                                 (float4*)out, (float4*)bufB, 0, 1);
    edge_kernel<<<edge_blocks, 256, 0, stream>>>(row, col, dis, bufA, bufB);

    // final: out += w2*bufB
    fuse_kernel<<<fuse_blocks, 256, 0, stream>>>((const float4*)bufB, dis, wsm, 2,
                                                 (float4*)out, (float4*)nullptr, 0, 0);
}

// Round 2
// 652.014 us; speedup vs baseline: 1.2426x; 1.2426x over previous
//
#include <hip/hip_runtime.h>

#define NN 100000
#define NE 1600000
#define D 64

// ---------------- build kernels ----------------

// One pass over edges: in-degree over col (for GCN norm) + out-counts over row (for CSR).
__global__ void hist_kernel(const int* __restrict__ row, const int* __restrict__ col,
                            int* __restrict__ degc, int* __restrict__ rowcnt) {
    int e = blockIdx.x * blockDim.x + threadIdx.x;
    if (e < NE) {
        atomicAdd(&degc[col[e]], 1);
        atomicAdd(&rowcnt[row[e]], 1);
    }
}

__global__ void dis_kernel(const int* __restrict__ degc, float* __restrict__ dis) {
    int i = blockIdx.x * blockDim.x + threadIdx.x;
    if (i < NN) dis[i] = rsqrtf((float)(degc[i] + 1)); // +1 self loop, always > 0
}

__global__ void softmax_kernel(const float* __restrict__ hw, float* __restrict__ wsm) {
    float m = fmaxf(fmaxf(hw[0], hw[1]), hw[2]);
    float e0 = expf(hw[0] - m), e1 = expf(hw[1] - m), e2 = expf(hw[2] - m);
    float s = e0 + e1 + e2;
    wsm[0] = e0 / s; wsm[1] = e1 / s; wsm[2] = e2 / s;
}

// Single-block exclusive scan of rowcnt[NN] -> rowptr[NN+1], cursor = rowptr copy.
__global__ void scan_kernel(const int* __restrict__ rowcnt,
                            int* __restrict__ rowptr, int* __restrict__ cursor) {
    __shared__ int part[1024];
    const int T = 1024;
    const int chunk = (NN + T - 1) / T; // 98
    int t = threadIdx.x;
    int beg = t * chunk, end = min(NN, beg + chunk);
    int s = 0;
    for (int i = beg; i < end; ++i) s += rowcnt[i];
    part[t] = s;
    __syncthreads();
    if (t == 0) {
        int run = 0;
        for (int i = 0; i < T; ++i) { int v = part[i]; part[i] = run; run += v; }
        rowptr[NN] = run;
    }
    __syncthreads();
    int run = part[t];
    for (int i = beg; i < end; ++i) {
        rowptr[i] = run; cursor[i] = run;
        run += rowcnt[i];
    }
}

// Scatter edges into CSR slots: adjacency col + precomputed edge norm.
__global__ void scatter_kernel(const int* __restrict__ row, const int* __restrict__ col,
                               const float* __restrict__ dis,
                               int* __restrict__ cursor,
                               int* __restrict__ adjc, float* __restrict__ adjw) {
    int e = blockIdx.x * blockDim.x + threadIdx.x;
    if (e >= NE) return;
    int r = row[e], c = col[e];
    int pos = atomicAdd(&cursor[r], 1);
    adjc[pos] = c;
    adjw[pos] = dis[r] * dis[c];
}

// ---------------- propagate kernels (gather, no atomics) ----------------
// One 64-lane wave per node; lane d = feature d.

__global__ void prop1_kernel(const float* __restrict__ x,
                             const int* __restrict__ rowptr,
                             const int* __restrict__ adjc, const float* __restrict__ adjw,
                             const float* __restrict__ dis,
                             float* __restrict__ h1) {
    int t = blockIdx.x * blockDim.x + threadIdx.x;
    int n = t >> 6, d = t & 63;
    if (n >= NN) return;
    int beg = rowptr[n], end = rowptr[n + 1];
    float di = dis[n];
    float acc = di * di * x[n * D + d];
    int j = beg;
    for (; j + 1 < end; j += 2) {
        int   c0 = adjc[j],     c1 = adjc[j + 1];
        float w0 = adjw[j],     w1 = adjw[j + 1];
        float v0 = x[c0 * D + d], v1 = x[c1 * D + d];
        acc += w0 * v0;
        acc += w1 * v1;
    }
    if (j < end) acc += adjw[j] * x[adjc[j] * D + d];
    h1[n * D + d] = acc;
}

// Second hop fused with final combine: out = w0*x + w1*h1 + w2*(A_norm @ h1)
__global__ void prop2_kernel(const float* __restrict__ x,
                             const float* __restrict__ h1,
                             const int* __restrict__ rowptr,
                             const int* __restrict__ adjc, const float* __restrict__ adjw,
                             const float* __restrict__ dis,
                             const float* __restrict__ wsm,
                             float* __restrict__ out) {
    int t = blockIdx.x * blockDim.x + threadIdx.x;
    int n = t >> 6, d = t & 63;
    if (n >= NN) return;
    int beg = rowptr[n], end = rowptr[n + 1];
    float di = dis[n];
    float h = h1[n * D + d];
    float acc = di * di * h;
    int j = beg;
    for (; j + 1 < end; j += 2) {
        int   c0 = adjc[j],      c1 = adjc[j + 1];
        float w0 = adjw[j],      w1 = adjw[j + 1];
        float v0 = h1[c0 * D + d], v1 = h1[c1 * D + d];
        acc += w0 * v0;
        acc += w1 * v1;
    }
    if (j < end) acc += adjw[j] * h1[adjc[j] * D + d];
    out[n * D + d] = wsm[0] * x[n * D + d] + wsm[1] * h + wsm[2] * acc;
}

// ---------------- launch ----------------

extern "C" void kernel_launch(void* const* d_in, const int* in_sizes, int n_in,
                              void* d_out, int out_size, void* d_ws, size_t ws_size,
                              hipStream_t stream) {
    const float* x   = (const float*)d_in[0];
    const int*   ei  = (const int*)d_in[1];   // [2, NE]
    const float* hw  = (const float*)d_in[2]; // [3]
    float*       out = (float*)d_out;

    const int* row = ei;       // scatter destination
    const int* col = ei + NE;  // gather source

    char* ws = (char*)d_ws;
    size_t off = 0;
    auto alloc = [&](size_t bytes) { size_t p = off; off += (bytes + 255) & ~(size_t)255; return p; };
    float* wsm    = (float*)(ws + alloc(16));
    int*   degc   = (int*)  (ws + alloc((size_t)NN * 4));
    int*   rowcnt = (int*)  (ws + alloc((size_t)NN * 4));
    int*   rowptr = (int*)  (ws + alloc((size_t)(NN + 1) * 4));
    int*   cursor = (int*)  (ws + alloc((size_t)NN * 4));
    float* dis    = (float*)(ws + alloc((size_t)NN * 4));
    int*   adjc   = (int*)  (ws + alloc((size_t)NE * 4));
    float* adjw   = (float*)(ws + alloc((size_t)NE * 4));
    float* h1     = (float*)(ws + alloc((size_t)NN * D * 4));

    hipMemsetAsync(degc, 0, (size_t)NN * 4, stream);
    hipMemsetAsync(rowcnt, 0, (size_t)NN * 4, stream);

    hist_kernel<<<(NE + 255) / 256, 256, 0, stream>>>(row, col, degc, rowcnt);
    dis_kernel<<<(NN + 255) / 256, 256, 0, stream>>>(degc, dis);
    softmax_kernel<<<1, 1, 0, stream>>>(hw, wsm);
    scan_kernel<<<1, 1024, 0, stream>>>(rowcnt, rowptr, cursor);
    scatter_kernel<<<(NE + 255) / 256, 256, 0, stream>>>(row, col, dis, cursor, adjc, adjw);

    const int prop_blocks = (NN * 64 + 255) / 256; // 25000
    prop1_kernel<<<prop_blocks, 256, 0, stream>>>(x, rowptr, adjc, adjw, dis, h1);
    prop2_kernel<<<prop_blocks, 256, 0, stream>>>(x, h1, rowptr, adjc, adjw, dis, wsm, out);
}

// Round 3
// 459.342 us; speedup vs baseline: 1.7637x; 1.4195x over previous
//
#include <hip/hip_runtime.h>

#define NN 100000
#define NE 1600000
#define D 64
#define SCAN_B 1024
#define SCAN_NB ((NN + SCAN_B - 1) / SCAN_B)   // 98

// ---------------- build kernels ----------------

// One pass over edges: in-degree over col (for GCN norm) + out-counts over row (for CSR).
__global__ void hist_kernel(const int* __restrict__ row, const int* __restrict__ col,
                            int* __restrict__ degc, int* __restrict__ rowcnt) {
    int e = blockIdx.x * blockDim.x + threadIdx.x;
    if (e < NE) {
        atomicAdd(&degc[col[e]], 1);
        atomicAdd(&rowcnt[row[e]], 1);
    }
}

__global__ void dis_kernel(const int* __restrict__ degc, float* __restrict__ dis) {
    int i = blockIdx.x * blockDim.x + threadIdx.x;
    if (i < NN) dis[i] = rsqrtf((float)(degc[i] + 1)); // +1 self loop, always > 0
}

__global__ void softmax_kernel(const float* __restrict__ hw, float* __restrict__ wsm) {
    float m = fmaxf(fmaxf(hw[0], hw[1]), hw[2]);
    float e0 = expf(hw[0] - m), e1 = expf(hw[1] - m), e2 = expf(hw[2] - m);
    float s = e0 + e1 + e2;
    wsm[0] = e0 / s; wsm[1] = e1 / s; wsm[2] = e2 / s;
}

// --- parallel exclusive scan of rowcnt[NN] -> rowptr[NN+1] (+cursor copy) ---

// Phase 1: per-block sums (coalesced loads, LDS tree reduce).
__global__ void scan_reduce(const int* __restrict__ rowcnt, int* __restrict__ partial) {
    __shared__ int lds[SCAN_B];
    int i = blockIdx.x * SCAN_B + threadIdx.x;
    lds[threadIdx.x] = (i < NN) ? rowcnt[i] : 0;
    __syncthreads();
    for (int s = SCAN_B / 2; s > 0; s >>= 1) {
        if (threadIdx.x < s) lds[threadIdx.x] += lds[threadIdx.x + s];
        __syncthreads();
    }
    if (threadIdx.x == 0) partial[blockIdx.x] = lds[0];
}

// Phase 2: exclusive scan of the 98 partials (single thread — trivial).
__global__ void scan_partials(int* __restrict__ partial) {
    if (threadIdx.x == 0) {
        int run = 0;
        for (int i = 0; i < SCAN_NB; ++i) { int v = partial[i]; partial[i] = run; run += v; }
        partial[SCAN_NB] = run;   // total == NE
    }
}

// Phase 3: per-block Hillis-Steele exclusive scan + block offset.
__global__ void scan_apply(const int* __restrict__ rowcnt, const int* __restrict__ partial,
                           int* __restrict__ rowptr, int* __restrict__ cursor) {
    __shared__ int lds[SCAN_B];
    int b = blockIdx.x;
    int i = b * SCAN_B + threadIdx.x;
    int v = (i < NN) ? rowcnt[i] : 0;
    lds[threadIdx.x] = v;
    __syncthreads();
    for (int s = 1; s < SCAN_B; s <<= 1) {
        int t = (threadIdx.x >= s) ? lds[threadIdx.x - s] : 0;
        __syncthreads();
        lds[threadIdx.x] += t;
        __syncthreads();
    }
    if (i < NN) {
        int excl = partial[b] + lds[threadIdx.x] - v;  // inclusive -> exclusive
        rowptr[i] = excl;
        cursor[i] = excl;
    }
    if (b == 0 && threadIdx.x == 0) rowptr[NN] = partial[SCAN_NB];
}

// Scatter edges into CSR slots: adjacency col + precomputed edge norm.
__global__ void scatter_kernel(const int* __restrict__ row, const int* __restrict__ col,
                               const float* __restrict__ dis,
                               int* __restrict__ cursor,
                               int* __restrict__ adjc, float* __restrict__ adjw) {
    int e = blockIdx.x * blockDim.x + threadIdx.x;
    if (e >= NE) return;
    int r = row[e], c = col[e];
    int pos = atomicAdd(&cursor[r], 1);
    adjc[pos] = c;
    adjw[pos] = dis[r] * dis[c];
}

// ---------------- propagate kernels (gather, no atomics) ----------------
// One 64-lane wave per node; lane d = feature d.

__global__ void prop1_kernel(const float* __restrict__ x,
                             const int* __restrict__ rowptr,
                             const int* __restrict__ adjc, const float* __restrict__ adjw,
                             const float* __restrict__ dis,
                             float* __restrict__ h1) {
    int t = blockIdx.x * blockDim.x + threadIdx.x;
    int n = t >> 6, d = t & 63;
    if (n >= NN) return;
    int beg = rowptr[n], end = rowptr[n + 1];
    float di = dis[n];
    float acc = di * di * x[n * D + d];
    int j = beg;
    for (; j + 1 < end; j += 2) {
        int   c0 = adjc[j],     c1 = adjc[j + 1];
        float w0 = adjw[j],     w1 = adjw[j + 1];
        float v0 = x[c0 * D + d], v1 = x[c1 * D + d];
        acc += w0 * v0;
        acc += w1 * v1;
    }
    if (j < end) acc += adjw[j] * x[adjc[j] * D + d];
    h1[n * D + d] = acc;
}

// Second hop fused with final combine: out = w0*x + w1*h1 + w2*(A_norm @ h1)
__global__ void prop2_kernel(const float* __restrict__ x,
                             const float* __restrict__ h1,
                             const int* __restrict__ rowptr,
                             const int* __restrict__ adjc, const float* __restrict__ adjw,
                             const float* __restrict__ dis,
                             const float* __restrict__ wsm,
                             float* __restrict__ out) {
    int t = blockIdx.x * blockDim.x + threadIdx.x;
    int n = t >> 6, d = t & 63;
    if (n >= NN) return;
    int beg = rowptr[n], end = rowptr[n + 1];
    float di = dis[n];
    float h = h1[n * D + d];
    float acc = di * di * h;
    int j = beg;
    for (; j + 1 < end; j += 2) {
        int   c0 = adjc[j],      c1 = adjc[j + 1];
        float w0 = adjw[j],      w1 = adjw[j + 1];
        float v0 = h1[c0 * D + d], v1 = h1[c1 * D + d];
        acc += w0 * v0;
        acc += w1 * v1;
    }
    if (j < end) acc += adjw[j] * h1[adjc[j] * D + d];
    out[n * D + d] = wsm[0] * x[n * D + d] + wsm[1] * h + wsm[2] * acc;
}

// ---------------- launch ----------------

extern "C" void kernel_launch(void* const* d_in, const int* in_sizes, int n_in,
                              void* d_out, int out_size, void* d_ws, size_t ws_size,
                              hipStream_t stream) {
    const float* x   = (const float*)d_in[0];
    const int*   ei  = (const int*)d_in[1];   // [2, NE]
    const float* hw  = (const float*)d_in[2]; // [3]
    float*       out = (float*)d_out;

    const int* row = ei;       // scatter destination
    const int* col = ei + NE;  // gather source

    char* ws = (char*)d_ws;
    size_t off = 0;
    auto alloc = [&](size_t bytes) { size_t p = off; off += (bytes + 255) & ~(size_t)255; return p; };
    float* wsm     = (float*)(ws + alloc(16));
    int*   degc    = (int*)  (ws + alloc((size_t)NN * 4));
    int*   rowcnt  = (int*)  (ws + alloc((size_t)NN * 4));
    int*   rowptr  = (int*)  (ws + alloc((size_t)(NN + 1) * 4));
    int*   cursor  = (int*)  (ws + alloc((size_t)NN * 4));
    int*   partial = (int*)  (ws + alloc((size_t)(SCAN_NB + 1) * 4));
    float* dis     = (float*)(ws + alloc((size_t)NN * 4));
    int*   adjc    = (int*)  (ws + alloc((size_t)NE * 4));
    float* adjw    = (float*)(ws + alloc((size_t)NE * 4));
    float* h1      = (float*)(ws + alloc((size_t)NN * D * 4));

    hipMemsetAsync(degc, 0, (size_t)NN * 4, stream);
    hipMemsetAsync(rowcnt, 0, (size_t)NN * 4, stream);

    hist_kernel<<<(NE + 255) / 256, 256, 0, stream>>>(row, col, degc, rowcnt);
    dis_kernel<<<(NN + 255) / 256, 256, 0, stream>>>(degc, dis);
    softmax_kernel<<<1, 1, 0, stream>>>(hw, wsm);

    scan_reduce  <<<SCAN_NB, SCAN_B, 0, stream>>>(rowcnt, partial);
    scan_partials<<<1, 64, 0, stream>>>(partial);
    scan_apply   <<<SCAN_NB, SCAN_B, 0, stream>>>(rowcnt, partial, rowptr, cursor);

    scatter_kernel<<<(NE + 255) / 256, 256, 0, stream>>>(row, col, dis, cursor, adjc, adjw);

    const int prop_blocks = (NN * 64 + 255) / 256; // 25000
    prop1_kernel<<<prop_blocks, 256, 0, stream>>>(x, rowptr, adjc, adjw, dis, h1);
    prop2_kernel<<<prop_blocks, 256, 0, stream>>>(x, h1, rowptr, adjc, adjw, dis, wsm, out);
}

// Round 4
// 409.988 us; speedup vs baseline: 1.9761x; 1.1204x over previous
//
#include <hip/hip_runtime.h>

#define NN 100000
#define NE 1600000
#define D 64
#define NXCD 8
#define SCAN_B 1024
#define SCAN_NB ((NN + SCAN_B - 1) / SCAN_B)   // 98

// ---------------- build kernels ----------------

__device__ __forceinline__ unsigned xcc_id() {
    unsigned v;
    asm volatile("s_getreg_b32 %0, hwreg(HW_REG_XCC_ID)" : "=s"(v));
    return v & (NXCD - 1);
}

// Per-XCD privatized histograms with workgroup-scope (L2-local, non-write-through)
// atomics. cnt8 layout: [0..7][NN] = in-degree over col, [8..15][NN] = out-count over row.
__global__ void hist8_kernel(const int* __restrict__ row, const int* __restrict__ col,
                             int* __restrict__ cnt8) {
    unsigned k = xcc_id();
    int* degc   = cnt8 + (size_t)k * NN;
    int* rowcnt = cnt8 + (size_t)(NXCD + k) * NN;
    int e = blockIdx.x * blockDim.x + threadIdx.x;
    if (e < NE) {
        __hip_atomic_fetch_add(&degc[col[e]], 1, __ATOMIC_RELAXED, __HIP_MEMORY_SCOPE_WORKGROUP);
        __hip_atomic_fetch_add(&rowcnt[row[e]], 1, __ATOMIC_RELAXED, __HIP_MEMORY_SCOPE_WORKGROUP);
    }
}

// Sum the 8 copies; fuse dis = rsqrt(deg+1).
__global__ void reduce8_kernel(const int* __restrict__ cnt8,
                               int* __restrict__ rowcnt, float* __restrict__ dis) {
    int i = blockIdx.x * blockDim.x + threadIdx.x;
    if (i >= NN) return;
    int dsum = 0, rsum = 0;
    #pragma unroll
    for (int k = 0; k < NXCD; ++k) {
        dsum += cnt8[(size_t)k * NN + i];
        rsum += cnt8[(size_t)(NXCD + k) * NN + i];
    }
    rowcnt[i] = rsum;
    dis[i] = rsqrtf((float)(dsum + 1)); // +1 self loop, always > 0
}

__global__ void softmax_kernel(const float* __restrict__ hw, float* __restrict__ wsm) {
    float m = fmaxf(fmaxf(hw[0], hw[1]), hw[2]);
    float e0 = expf(hw[0] - m), e1 = expf(hw[1] - m), e2 = expf(hw[2] - m);
    float s = e0 + e1 + e2;
    wsm[0] = e0 / s; wsm[1] = e1 / s; wsm[2] = e2 / s;
}

// --- parallel exclusive scan of rowcnt[NN] -> rowptr[NN+1] (+cursor copy) ---

__global__ void scan_reduce(const int* __restrict__ rowcnt, int* __restrict__ partial) {
    __shared__ int lds[SCAN_B];
    int i = blockIdx.x * SCAN_B + threadIdx.x;
    lds[threadIdx.x] = (i < NN) ? rowcnt[i] : 0;
    __syncthreads();
    for (int s = SCAN_B / 2; s > 0; s >>= 1) {
        if (threadIdx.x < s) lds[threadIdx.x] += lds[threadIdx.x + s];
        __syncthreads();
    }
    if (threadIdx.x == 0) partial[blockIdx.x] = lds[0];
}

__global__ void scan_partials(int* __restrict__ partial) {
    if (threadIdx.x == 0) {
        int run = 0;
        for (int i = 0; i < SCAN_NB; ++i) { int v = partial[i]; partial[i] = run; run += v; }
        partial[SCAN_NB] = run;   // total == NE
    }
}

__global__ void scan_apply(const int* __restrict__ rowcnt, const int* __restrict__ partial,
                           int* __restrict__ rowptr, int* __restrict__ cursor) {
    __shared__ int lds[SCAN_B];
    int b = blockIdx.x;
    int i = b * SCAN_B + threadIdx.x;
    int v = (i < NN) ? rowcnt[i] : 0;
    lds[threadIdx.x] = v;
    __syncthreads();
    for (int s = 1; s < SCAN_B; s <<= 1) {
        int t = (threadIdx.x >= s) ? lds[threadIdx.x - s] : 0;
        __syncthreads();
        lds[threadIdx.x] += t;
        __syncthreads();
    }
    if (i < NN) {
        int excl = partial[b] + lds[threadIdx.x] - v;
        rowptr[i] = excl;
        cursor[i] = excl;
    }
    if (b == 0 && threadIdx.x == 0) rowptr[NN] = partial[SCAN_NB];
}

// Scatter edges into CSR slots (adjacency col only; norm recomputed in prop).
__global__ void scatter_kernel(const int* __restrict__ row, const int* __restrict__ col,
                               int* __restrict__ cursor, int* __restrict__ adjc) {
    int e = blockIdx.x * blockDim.x + threadIdx.x;
    if (e >= NE) return;
    int pos = atomicAdd(&cursor[row[e]], 1);
    adjc[pos] = col[e];
}

// ---------------- propagate kernels (gather, no atomics) ----------------
// One 64-lane wave per node; lane d = feature d.  h = di * (di*x_n + sum dis_c * x_c)

__global__ void prop1_kernel(const float* __restrict__ x,
                             const int* __restrict__ rowptr,
                             const int* __restrict__ adjc,
                             const float* __restrict__ dis,
                             float* __restrict__ h1) {
    int t = blockIdx.x * blockDim.x + threadIdx.x;
    int n = t >> 6, d = t & 63;
    if (n >= NN) return;
    int beg = rowptr[n], end = rowptr[n + 1];
    float di = dis[n];
    float acc = di * x[n * D + d];
    int j = beg;
    for (; j + 4 <= end; j += 4) {
        int c0 = adjc[j], c1 = adjc[j + 1], c2 = adjc[j + 2], c3 = adjc[j + 3];
        float w0 = dis[c0], w1 = dis[c1], w2 = dis[c2], w3 = dis[c3];
        acc += w0 * x[c0 * D + d];
        acc += w1 * x[c1 * D + d];
        acc += w2 * x[c2 * D + d];
        acc += w3 * x[c3 * D + d];
    }
    for (; j < end; ++j) { int c = adjc[j]; acc += dis[c] * x[c * D + d]; }
    h1[n * D + d] = di * acc;
}

// Second hop fused with final combine: out = w0*x + w1*h1 + w2*(A_norm @ h1)
__global__ void prop2_kernel(const float* __restrict__ x,
                             const float* __restrict__ h1,
                             const int* __restrict__ rowptr,
                             const int* __restrict__ adjc,
                             const float* __restrict__ dis,
                             const float* __restrict__ wsm,
                             float* __restrict__ out) {
    int t = blockIdx.x * blockDim.x + threadIdx.x;
    int n = t >> 6, d = t & 63;
    if (n >= NN) return;
    int beg = rowptr[n], end = rowptr[n + 1];
    float di = dis[n];
    float h = h1[n * D + d];
    float acc = di * h;
    int j = beg;
    for (; j + 4 <= end; j += 4) {
        int c0 = adjc[j], c1 = adjc[j + 1], c2 = adjc[j + 2], c3 = adjc[j + 3];
        float w0 = dis[c0], w1 = dis[c1], w2 = dis[c2], w3 = dis[c3];
        acc += w0 * h1[c0 * D + d];
        acc += w1 * h1[c1 * D + d];
        acc += w2 * h1[c2 * D + d];
        acc += w3 * h1[c3 * D + d];
    }
    for (; j < end; ++j) { int c = adjc[j]; acc += dis[c] * h1[c * D + d]; }
    out[n * D + d] = wsm[0] * x[n * D + d] + wsm[1] * h + wsm[2] * (di * acc);
}

// ---------------- launch ----------------

extern "C" void kernel_launch(void* const* d_in, const int* in_sizes, int n_in,
                              void* d_out, int out_size, void* d_ws, size_t ws_size,
                              hipStream_t stream) {
    const float* x   = (const float*)d_in[0];
    const int*   ei  = (const int*)d_in[1];   // [2, NE]
    const float* hw  = (const float*)d_in[2]; // [3]
    float*       out = (float*)d_out;

    const int* row = ei;       // scatter destination
    const int* col = ei + NE;  // gather source

    char* ws = (char*)d_ws;
    size_t off = 0;
    auto alloc = [&](size_t bytes) { size_t p = off; off += (bytes + 255) & ~(size_t)255; return p; };
    float* wsm     = (float*)(ws + alloc(16));
    int*   cnt8    = (int*)  (ws + alloc((size_t)2 * NXCD * NN * 4));
    int*   rowcnt  = (int*)  (ws + alloc((size_t)NN * 4));
    int*   rowptr  = (int*)  (ws + alloc((size_t)(NN + 1) * 4));
    int*   cursor  = (int*)  (ws + alloc((size_t)NN * 4));
    int*   partial = (int*)  (ws + alloc((size_t)(SCAN_NB + 1) * 4));
    float* dis     = (float*)(ws + alloc((size_t)NN * 4));
    int*   adjc    = (int*)  (ws + alloc((size_t)NE * 4));
    float* h1      = (float*)(ws + alloc((size_t)NN * D * 4));

    hipMemsetAsync(cnt8, 0, (size_t)2 * NXCD * NN * 4, stream);

    hist8_kernel<<<(NE + 255) / 256, 256, 0, stream>>>(row, col, cnt8);
    reduce8_kernel<<<(NN + 255) / 256, 256, 0, stream>>>(cnt8, rowcnt, dis);
    softmax_kernel<<<1, 1, 0, stream>>>(hw, wsm);

    scan_reduce  <<<SCAN_NB, SCAN_B, 0, stream>>>(rowcnt, partial);
    scan_partials<<<1, 64, 0, stream>>>(partial);
    scan_apply   <<<SCAN_NB, SCAN_B, 0, stream>>>(rowcnt, partial, rowptr, cursor);

    scatter_kernel<<<(NE + 255) / 256, 256, 0, stream>>>(row, col, cursor, adjc);

    const int prop_blocks = (NN * 64 + 255) / 256; // 25000
    prop1_kernel<<<prop_blocks, 256, 0, stream>>>(x, rowptr, adjc, dis, h1);
    prop2_kernel<<<prop_blocks, 256, 0, stream>>>(x, h1, rowptr, adjc, dis, wsm, out);
}

// Round 5
// 307.222 us; speedup vs baseline: 2.6371x; 1.3345x over previous
//
#include <hip/hip_runtime.h>

#define NN 100000
#define NE 1600000
#define D 64
#define NXCD 8

#define BKT 128                          // row buckets
#define BROWS ((NN + BKT - 1) / BKT)     // 782 rows per bucket (<=1024)
#define P1_NB 1024                       // pass-1 blocks
#define EPB ((NE + P1_NB - 1) / P1_NB)   // 1563 edges per pass-1 block
#define SCN (BKT * P1_NB)                // 131072 scan elements

// ---------------- degree / norm ----------------

__device__ __forceinline__ unsigned xcc_id() {
    unsigned v;
    asm volatile("s_getreg_b32 %0, hwreg(HW_REG_XCC_ID)" : "=s"(v));
    return v & (NXCD - 1);
}

// Per-XCD privatized in-degree histogram over col (workgroup-scope = L2-local atomics).
__global__ void hist8_kernel(const int* __restrict__ col, int* __restrict__ cnt8) {
    unsigned k = xcc_id();
    int* degc = cnt8 + (size_t)k * NN;
    int e = blockIdx.x * blockDim.x + threadIdx.x;
    if (e < NE)
        __hip_atomic_fetch_add(&degc[col[e]], 1, __ATOMIC_RELAXED, __HIP_MEMORY_SCOPE_WORKGROUP);
}

__global__ void reduce8_kernel(const int* __restrict__ cnt8, float* __restrict__ dis) {
    int i = blockIdx.x * blockDim.x + threadIdx.x;
    if (i >= NN) return;
    int dsum = 0;
    #pragma unroll
    for (int k = 0; k < NXCD; ++k) dsum += cnt8[(size_t)k * NN + i];
    dis[i] = rsqrtf((float)(dsum + 1)); // +1 self loop, always > 0
}

__global__ void softmax_kernel(const float* __restrict__ hw, float* __restrict__ wsm) {
    float m = fmaxf(fmaxf(hw[0], hw[1]), hw[2]);
    float e0 = expf(hw[0] - m), e1 = expf(hw[1] - m), e2 = expf(hw[2] - m);
    float s = e0 + e1 + e2;
    wsm[0] = e0 / s; wsm[1] = e1 / s; wsm[2] = e2 / s;
}

// ---------------- counting-sort CSR build (no global atomics) ----------------

// Pass 1a: per-block bucket histogram (LDS atomics), cnt[bkt][blk].
__global__ void p1_count(const int* __restrict__ row, int* __restrict__ cnt) {
    __shared__ int h[BKT];
    for (int i = threadIdx.x; i < BKT; i += blockDim.x) h[i] = 0;
    __syncthreads();
    int beg = blockIdx.x * EPB, end = min(NE, beg + EPB);
    for (int e = beg + threadIdx.x; e < end; e += blockDim.x)
        atomicAdd(&h[row[e] / BROWS], 1);
    __syncthreads();
    for (int i = threadIdx.x; i < BKT; i += blockDim.x)
        cnt[(size_t)i * P1_NB + blockIdx.x] = h[i];
}

// Pass 1b: exclusive scan of cnt[SCN] in place (bucket-major order).
__global__ void __launch_bounds__(1024) p1_scan(int* __restrict__ cnt) {
    __shared__ int sums[1024];
    const int per = SCN / 1024; // 128
    int t = threadIdx.x;
    int s = 0;
    for (int i = t * per; i < (t + 1) * per; ++i) s += cnt[i];
    sums[t] = s;
    __syncthreads();
    for (int st = 1; st < 1024; st <<= 1) {
        int v = (t >= st) ? sums[t - st] : 0;
        __syncthreads();
        sums[t] += v;
        __syncthreads();
    }
    int run = sums[t] - s; // exclusive
    for (int i = t * per; i < (t + 1) * per; ++i) { int v = cnt[i]; cnt[i] = run; run += v; }
}

// Pass 1c: scatter packed (col,row) into bucket-contiguous storage.
__global__ void p1_scatter(const int* __restrict__ row, const int* __restrict__ col,
                           const int* __restrict__ base,
                           unsigned long long* __restrict__ buck) {
    __shared__ int cur[BKT];
    for (int i = threadIdx.x; i < BKT; i += blockDim.x)
        cur[i] = base[(size_t)i * P1_NB + blockIdx.x];
    __syncthreads();
    int beg = blockIdx.x * EPB, end = min(NE, beg + EPB);
    for (int e = beg + threadIdx.x; e < end; e += blockDim.x) {
        int r = row[e], c = col[e];
        int pos = atomicAdd(&cur[r / BROWS], 1); // LDS atomic
        buck[pos] = ((unsigned long long)(unsigned)c << 32) | (unsigned)r;
    }
}

// Pass 2: one block per bucket — LDS row-count, LDS scan -> rowptr, local scatter -> adjc.
__global__ void __launch_bounds__(1024) p2_build(const int* __restrict__ base,
                                                 const unsigned long long* __restrict__ buck,
                                                 int* __restrict__ adjc,
                                                 int* __restrict__ rowptr) {
    __shared__ int ca[BROWS];   // counts -> global-position cursor
    __shared__ int sums[1024];
    int b = blockIdx.x, t = threadIdx.x;
    int row0 = b * BROWS;
    int nrows = min(BROWS, NN - row0);
    int ebeg = base[(size_t)b * P1_NB];
    int eend = (b + 1 < BKT) ? base[(size_t)(b + 1) * P1_NB] : NE;

    for (int i = t; i < nrows; i += 1024) ca[i] = 0;
    __syncthreads();
    for (int e = ebeg + t; e < eend; e += 1024)
        atomicAdd(&ca[(int)(buck[e] & 0xffffffffu) - row0], 1);
    __syncthreads();
    // exclusive scan over nrows (<=1024): one element per thread
    int v = (t < nrows) ? ca[t] : 0;
    sums[t] = v;
    __syncthreads();
    for (int st = 1; st < 1024; st <<= 1) {
        int u = (t >= st) ? sums[t - st] : 0;
        __syncthreads();
        sums[t] += u;
        __syncthreads();
    }
    int excl = sums[t] - v;
    if (t < nrows) {
        rowptr[row0 + t] = ebeg + excl;
        ca[t] = ebeg + excl; // cursor holds global position
    }
    if (b == 0 && t == 0) rowptr[NN] = NE;
    __syncthreads();
    for (int e = ebeg + t; e < eend; e += 1024) {
        unsigned long long p = buck[e];
        int r = (int)(p & 0xffffffffu);
        int c = (int)(p >> 32);
        int pos = atomicAdd(&ca[r - row0], 1); // LDS atomic
        adjc[pos] = c;
    }
}

// ---------------- propagate kernels (gather, no atomics) ----------------
// One 64-lane wave per node; lane d = feature d.  h = di * (di*x_n + sum dis_c * x_c)

__global__ void prop1_kernel(const float* __restrict__ x,
                             const int* __restrict__ rowptr,
                             const int* __restrict__ adjc,
                             const float* __restrict__ dis,
                             float* __restrict__ h1) {
    int t = blockIdx.x * blockDim.x + threadIdx.x;
    int n = t >> 6, d = t & 63;
    if (n >= NN) return;
    int beg = rowptr[n], end = rowptr[n + 1];
    float di = dis[n];
    float acc = di * x[n * D + d];
    int j = beg;
    for (; j + 4 <= end; j += 4) {
        int c0 = adjc[j], c1 = adjc[j + 1], c2 = adjc[j + 2], c3 = adjc[j + 3];
        float w0 = dis[c0], w1 = dis[c1], w2 = dis[c2], w3 = dis[c3];
        acc += w0 * x[c0 * D + d];
        acc += w1 * x[c1 * D + d];
        acc += w2 * x[c2 * D + d];
        acc += w3 * x[c3 * D + d];
    }
    for (; j < end; ++j) { int c = adjc[j]; acc += dis[c] * x[c * D + d]; }
    h1[n * D + d] = di * acc;
}

__global__ void prop2_kernel(const float* __restrict__ x,
                             const float* __restrict__ h1,
                             const int* __restrict__ rowptr,
                             const int* __restrict__ adjc,
                             const float* __restrict__ dis,
                             const float* __restrict__ wsm,
                             float* __restrict__ out) {
    int t = blockIdx.x * blockDim.x + threadIdx.x;
    int n = t >> 6, d = t & 63;
    if (n >= NN) return;
    int beg = rowptr[n], end = rowptr[n + 1];
    float di = dis[n];
    float h = h1[n * D + d];
    float acc = di * h;
    int j = beg;
    for (; j + 4 <= end; j += 4) {
        int c0 = adjc[j], c1 = adjc[j + 1], c2 = adjc[j + 2], c3 = adjc[j + 3];
        float w0 = dis[c0], w1 = dis[c1], w2 = dis[c2], w3 = dis[c3];
        acc += w0 * h1[c0 * D + d];
        acc += w1 * h1[c1 * D + d];
        acc += w2 * h1[c2 * D + d];
        acc += w3 * h1[c3 * D + d];
    }
    for (; j < end; ++j) { int c = adjc[j]; acc += dis[c] * h1[c * D + d]; }
    out[n * D + d] = wsm[0] * x[n * D + d] + wsm[1] * h + wsm[2] * (di * acc);
}

// ---------------- launch ----------------

extern "C" void kernel_launch(void* const* d_in, const int* in_sizes, int n_in,
                              void* d_out, int out_size, void* d_ws, size_t ws_size,
                              hipStream_t stream) {
    const float* x   = (const float*)d_in[0];
    const int*   ei  = (const int*)d_in[1];   // [2, NE]
    const float* hw  = (const float*)d_in[2]; // [3]
    float*       out = (float*)d_out;

    const int* row = ei;       // scatter destination
    const int* col = ei + NE;  // gather source

    char* ws = (char*)d_ws;
    size_t off = 0;
    auto alloc = [&](size_t bytes) { size_t p = off; off += (bytes + 255) & ~(size_t)255; return p; };
    float*              wsm    = (float*)(ws + alloc(16));
    int*                cnt8   = (int*)  (ws + alloc((size_t)NXCD * NN * 4));
    float*              dis    = (float*)(ws + alloc((size_t)NN * 4));
    int*                cnt    = (int*)  (ws + alloc((size_t)SCN * 4));
    unsigned long long* buck   = (unsigned long long*)(ws + alloc((size_t)NE * 8));
    int*                adjc   = (int*)  (ws + alloc((size_t)NE * 4));
    int*                rowptr = (int*)  (ws + alloc((size_t)(NN + 1) * 4));
    float*              h1     = (float*)(ws + alloc((size_t)NN * D * 4));

    hipMemsetAsync(cnt8, 0, (size_t)NXCD * NN * 4, stream);

    hist8_kernel<<<(NE + 255) / 256, 256, 0, stream>>>(col, cnt8);
    reduce8_kernel<<<(NN + 255) / 256, 256, 0, stream>>>(cnt8, dis);
    softmax_kernel<<<1, 1, 0, stream>>>(hw, wsm);

    p1_count  <<<P1_NB, 256, 0, stream>>>(row, cnt);
    p1_scan   <<<1, 1024, 0, stream>>>(cnt);
    p1_scatter<<<P1_NB, 256, 0, stream>>>(row, col, cnt, buck);
    p2_build  <<<BKT, 1024, 0, stream>>>(cnt, buck, adjc, rowptr);

    const int prop_blocks = (NN * 64 + 255) / 256; // 25000
    prop1_kernel<<<prop_blocks, 256, 0, stream>>>(x, rowptr, adjc, dis, h1);
    prop2_kernel<<<prop_blocks, 256, 0, stream>>>(x, h1, rowptr, adjc, dis, wsm, out);
}

// Round 6
// 285.854 us; speedup vs baseline: 2.8342x; 1.0748x over previous
//
#include <hip/hip_runtime.h>

#define NN 100000
#define NE 1600000
#define D 64
#define NXCD 8

#define BKT 128                          // row buckets
#define BROWS ((NN + BKT - 1) / BKT)     // 782 rows per bucket (<=1024)
#define P1_NB 512                        // pass-1 blocks
#define P1_T 512                         // pass-1 threads per block
#define EPB ((NE + P1_NB - 1) / P1_NB)   // 3125 edges per pass-1 block
#define SCN (BKT * P1_NB)                // 65536 scan elements

// ---------------- degree / norm ----------------

__device__ __forceinline__ unsigned xcc_id() {
    unsigned v;
    asm volatile("s_getreg_b32 %0, hwreg(HW_REG_XCC_ID)" : "=s"(v));
    return v & (NXCD - 1);
}

__global__ void softmax_kernel(const float* __restrict__ hw, float* __restrict__ wsm) {
    float m = fmaxf(fmaxf(hw[0], hw[1]), hw[2]);
    float e0 = expf(hw[0] - m), e1 = expf(hw[1] - m), e2 = expf(hw[2] - m);
    float s = e0 + e1 + e2;
    wsm[0] = e0 / s; wsm[1] = e1 / s; wsm[2] = e2 / s;
}

// Pass 1a (fused): per-block row-bucket histogram (LDS) + per-XCD col-degree
// histogram (workgroup-scope = L2-local atomics).
__global__ void __launch_bounds__(P1_T) p1_count(const int* __restrict__ row,
                                                 const int* __restrict__ col,
                                                 int* __restrict__ cnt,
                                                 int* __restrict__ cnt8) {
    __shared__ int h[BKT];
    for (int i = threadIdx.x; i < BKT; i += P1_T) h[i] = 0;
    __syncthreads();
    unsigned k = xcc_id();
    int* degc = cnt8 + (size_t)k * NN;
    int beg = blockIdx.x * EPB, end = min(NE, beg + EPB);
    for (int e = beg + threadIdx.x; e < end; e += P1_T) {
        atomicAdd(&h[row[e] / BROWS], 1);
        __hip_atomic_fetch_add(&degc[col[e]], 1, __ATOMIC_RELAXED, __HIP_MEMORY_SCOPE_WORKGROUP);
    }
    __syncthreads();
    for (int i = threadIdx.x; i < BKT; i += P1_T)
        cnt[(size_t)i * P1_NB + blockIdx.x] = h[i];
}

// Sum the 8 degree copies -> dis = rsqrt(deg+1), dsi = 1/dis.
__global__ void reduce8_kernel(const int* __restrict__ cnt8,
                               float* __restrict__ dis, float* __restrict__ dsi) {
    int i = blockIdx.x * blockDim.x + threadIdx.x;
    if (i >= NN) return;
    int dsum = 0;
    #pragma unroll
    for (int k = 0; k < NXCD; ++k) dsum += cnt8[(size_t)k * NN + i];
    float dg = (float)(dsum + 1);          // +1 self loop, always > 0
    dis[i] = rsqrtf(dg);
    dsi[i] = sqrtf(dg);
}

// y1 = dis (x) x   (row-broadcast scale), float4 vectorized.
__global__ void scale_kernel(const float4* __restrict__ x, const float* __restrict__ dis,
                             float4* __restrict__ y1) {
    int idx = blockIdx.x * blockDim.x + threadIdx.x; // over NN*16
    if (idx >= NN * (D / 4)) return;
    float s = dis[idx >> 4];
    float4 v = x[idx];
    v.x *= s; v.y *= s; v.z *= s; v.w *= s;
    y1[idx] = v;
}

// Pass 1b: exclusive scan of cnt[SCN] in place (bucket-major order).
__global__ void __launch_bounds__(1024) p1_scan(int* __restrict__ cnt) {
    __shared__ int sums[1024];
    const int per = SCN / 1024; // 64
    int t = threadIdx.x;
    int s = 0;
    for (int i = t * per; i < (t + 1) * per; ++i) s += cnt[i];
    sums[t] = s;
    __syncthreads();
    for (int st = 1; st < 1024; st <<= 1) {
        int v = (t >= st) ? sums[t - st] : 0;
        __syncthreads();
        sums[t] += v;
        __syncthreads();
    }
    int run = sums[t] - s; // exclusive
    for (int i = t * per; i < (t + 1) * per; ++i) { int v = cnt[i]; cnt[i] = run; run += v; }
}

// Pass 1c: scatter packed (col,row) into bucket-contiguous storage.
__global__ void __launch_bounds__(P1_T) p1_scatter(const int* __restrict__ row,
                                                   const int* __restrict__ col,
                                                   const int* __restrict__ base,
                                                   unsigned long long* __restrict__ buck) {
    __shared__ int cur[BKT];
    for (int i = threadIdx.x; i < BKT; i += P1_T)
        cur[i] = base[(size_t)i * P1_NB + blockIdx.x];
    __syncthreads();
    int beg = blockIdx.x * EPB, end = min(NE, beg + EPB);
    for (int e = beg + threadIdx.x; e < end; e += P1_T) {
        int r = row[e], c = col[e];
        int pos = atomicAdd(&cur[r / BROWS], 1); // LDS atomic
        buck[pos] = ((unsigned long long)(unsigned)c << 32) | (unsigned)r;
    }
}

// Pass 2: one block per bucket — LDS row-count, LDS scan -> rowptr, local scatter -> adjc.
__global__ void __launch_bounds__(1024) p2_build(const int* __restrict__ base,
                                                 const unsigned long long* __restrict__ buck,
                                                 int* __restrict__ adjc,
                                                 int* __restrict__ rowptr) {
    __shared__ int ca[BROWS];
    __shared__ int sums[1024];
    int b = blockIdx.x, t = threadIdx.x;
    int row0 = b * BROWS;
    int nrows = min(BROWS, NN - row0);
    int ebeg = base[(size_t)b * P1_NB];
    int eend = (b + 1 < BKT) ? base[(size_t)(b + 1) * P1_NB] : NE;

    for (int i = t; i < nrows; i += 1024) ca[i] = 0;
    __syncthreads();
    for (int e = ebeg + t; e < eend; e += 1024)
        atomicAdd(&ca[(int)(buck[e] & 0xffffffffu) - row0], 1);
    __syncthreads();
    int v = (t < nrows) ? ca[t] : 0;
    sums[t] = v;
    __syncthreads();
    for (int st = 1; st < 1024; st <<= 1) {
        int u = (t >= st) ? sums[t - st] : 0;
        __syncthreads();
        sums[t] += u;
        __syncthreads();
    }
    int excl = sums[t] - v;
    if (t < nrows) {
        rowptr[row0 + t] = ebeg + excl;
        ca[t] = ebeg + excl;
    }
    if (b == 0 && t == 0) rowptr[NN] = NE;
    __syncthreads();
    for (int e = ebeg + t; e < eend; e += 1024) {
        unsigned long long p = buck[e];
        int r = (int)(p & 0xffffffffu);
        int c = (int)(p >> 32);
        int pos = atomicAdd(&ca[r - row0], 1); // LDS atomic
        adjc[pos] = c;
    }
}

// ---------------- propagate kernels (gather, no atomics) ----------------
// One 64-lane wave per node; lane d = feature d.
// h = di * (y[n] + sum_c y[c]);  y_next = dis (x) h = di^2 * acc.

__global__ void prop1_kernel(const int* __restrict__ rowptr,
                             const int* __restrict__ adjc,
                             const float* __restrict__ dis,
                             const float* __restrict__ y1,
                             float* __restrict__ y2) {
    int t = blockIdx.x * blockDim.x + threadIdx.x;
    int n = t >> 6, d = t & 63;
    if (n >= NN) return;
    int beg = rowptr[n], end = rowptr[n + 1];
    float acc = y1[n * D + d];            // self-loop term
    int j = beg;
    for (; j + 8 <= end; j += 8) {
        int c[8]; float v[8];
        #pragma unroll
        for (int u = 0; u < 8; ++u) c[u] = adjc[j + u];
        #pragma unroll
        for (int u = 0; u < 8; ++u) v[u] = y1[c[u] * D + d];
        #pragma unroll
        for (int u = 0; u < 8; ++u) acc += v[u];
    }
    for (; j < end; ++j) acc += y1[adjc[j] * D + d];
    float di = dis[n];
    y2[n * D + d] = di * di * acc;        // dis * h1
}

// out = w0*x + w1*(dsi*y2[n]) + w2*di*(y2[n] + sum_c y2[c])
__global__ void prop2_kernel(const float* __restrict__ x,
                             const int* __restrict__ rowptr,
                             const int* __restrict__ adjc,
                             const float* __restrict__ dis,
                             const float* __restrict__ dsi,
                             const float* __restrict__ y2,
                             const float* __restrict__ wsm,
                             float* __restrict__ out) {
    int t = blockIdx.x * blockDim.x + threadIdx.x;
    int n = t >> 6, d = t & 63;
    if (n >= NN) return;
    int beg = rowptr[n], end = rowptr[n + 1];
    float yn = y2[n * D + d];
    float acc = yn;                        // self-loop term
    int j = beg;
    for (; j + 8 <= end; j += 8) {
        int c[8]; float v[8];
        #pragma unroll
        for (int u = 0; u < 8; ++u) c[u] = adjc[j + u];
        #pragma unroll
        for (int u = 0; u < 8; ++u) v[u] = y2[c[u] * D + d];
        #pragma unroll
        for (int u = 0; u < 8; ++u) acc += v[u];
    }
    for (; j < end; ++j) acc += y2[adjc[j] * D + d];
    float di = dis[n];
    out[n * D + d] = wsm[0] * x[n * D + d] + wsm[1] * (dsi[n] * yn) + wsm[2] * (di * acc);
}

// ---------------- launch ----------------

extern "C" void kernel_launch(void* const* d_in, const int* in_sizes, int n_in,
                              void* d_out, int out_size, void* d_ws, size_t ws_size,
                              hipStream_t stream) {
    const float* x   = (const float*)d_in[0];
    const int*   ei  = (const int*)d_in[1];   // [2, NE]
    const float* hw  = (const float*)d_in[2]; // [3]
    float*       out = (float*)d_out;

    const int* row = ei;       // scatter destination
    const int* col = ei + NE;  // gather source

    char* ws = (char*)d_ws;
    size_t off = 0;
    auto alloc = [&](size_t bytes) { size_t p = off; off += (bytes + 255) & ~(size_t)255; return p; };
    float*              wsm    = (float*)(ws + alloc(16));
    // buck (12.8 MB) aliases cnt8 (3.2 MB): cnt8 dead after reduce8, buck written later.
    unsigned long long* buck   = (unsigned long long*)(ws + alloc((size_t)NE * 8));
    int*                cnt8   = (int*)buck;
    float*              dis    = (float*)(ws + alloc((size_t)NN * 4));
    float*              dsi    = (float*)(ws + alloc((size_t)NN * 4));
    int*                cnt    = (int*)  (ws + alloc((size_t)SCN * 4));
    int*                adjc   = (int*)  (ws + alloc((size_t)NE * 4));
    int*                rowptr = (int*)  (ws + alloc((size_t)(NN + 1) * 4));
    float*              y1     = (float*)(ws + alloc((size_t)NN * D * 4));
    float*              y2     = (float*)(ws + alloc((size_t)NN * D * 4));

    hipMemsetAsync(cnt8, 0, (size_t)NXCD * NN * 4, stream);

    p1_count<<<P1_NB, P1_T, 0, stream>>>(row, col, cnt, cnt8);
    reduce8_kernel<<<(NN + 255) / 256, 256, 0, stream>>>(cnt8, dis, dsi);
    softmax_kernel<<<1, 1, 0, stream>>>(hw, wsm);
    scale_kernel<<<(NN * (D / 4) + 255) / 256, 256, 0, stream>>>((const float4*)x, dis, (float4*)y1);

    p1_scan   <<<1, 1024, 0, stream>>>(cnt);
    p1_scatter<<<P1_NB, P1_T, 0, stream>>>(row, col, cnt, buck);
    p2_build  <<<BKT, 1024, 0, stream>>>(cnt, buck, adjc, rowptr);

    const int prop_blocks = (NN * 64 + 255) / 256; // 25000
    prop1_kernel<<<prop_blocks, 256, 0, stream>>>(rowptr, adjc, dis, y1, y2);
    prop2_kernel<<<prop_blocks, 256, 0, stream>>>(x, rowptr, adjc, dis, dsi, y2, wsm, out);
}

// Round 7
// 269.637 us; speedup vs baseline: 3.0046x; 1.0601x over previous
//
#include <hip/hip_runtime.h>

#define NN 100000
#define NE 1600000
#define D 64
#define NXCD 8

#define BKT 128                          // row buckets
#define BROWS ((NN + BKT - 1) / BKT)     // 782 rows per bucket (<=1024, fits 10 bits)
#define P1_NB 512                        // pass-1 blocks
#define P1_T 512                         // pass-1 threads per block
#define EPB ((NE + P1_NB - 1) / P1_NB)   // 3125 edges per pass-1 block
#define SCN (BKT * P1_NB)                // 65536 scan elements

typedef unsigned short u16;
typedef unsigned int u32;

// ---------------- bf16 helpers (bit-level, RNE) ----------------

__device__ __forceinline__ float bf2f(u16 u) {
    union { u32 i; float f; } x; x.i = ((u32)u) << 16; return x.f;
}
__device__ __forceinline__ u16 f2bf(float f) {
    union { float f; u32 i; } x; x.f = f;
    u32 r = x.i + 0x7FFF + ((x.i >> 16) & 1);   // round-to-nearest-even
    return (u16)(r >> 16);
}

// ---------------- degree / norm ----------------

__device__ __forceinline__ unsigned xcc_id() {
    unsigned v;
    asm volatile("s_getreg_b32 %0, hwreg(HW_REG_XCC_ID)" : "=s"(v));
    return v & (NXCD - 1);
}

__global__ void softmax_kernel(const float* __restrict__ hw, float* __restrict__ wsm) {
    float m = fmaxf(fmaxf(hw[0], hw[1]), hw[2]);
    float e0 = expf(hw[0] - m), e1 = expf(hw[1] - m), e2 = expf(hw[2] - m);
    float s = e0 + e1 + e2;
    wsm[0] = e0 / s; wsm[1] = e1 / s; wsm[2] = e2 / s;
}

// Pass 1a (fused): per-block row-bucket histogram (LDS) + per-XCD col-degree
// histogram (workgroup-scope = L2-local atomics).
__global__ void __launch_bounds__(P1_T) p1_count(const int* __restrict__ row,
                                                 const int* __restrict__ col,
                                                 int* __restrict__ cnt,
                                                 int* __restrict__ cnt8) {
    __shared__ int h[BKT];
    for (int i = threadIdx.x; i < BKT; i += P1_T) h[i] = 0;
    __syncthreads();
    unsigned k = xcc_id();
    int* degc = cnt8 + (size_t)k * NN;
    int beg = blockIdx.x * EPB, end = min(NE, beg + EPB);
    for (int e = beg + threadIdx.x; e < end; e += P1_T) {
        atomicAdd(&h[row[e] / BROWS], 1);
        __hip_atomic_fetch_add(&degc[col[e]], 1, __ATOMIC_RELAXED, __HIP_MEMORY_SCOPE_WORKGROUP);
    }
    __syncthreads();
    for (int i = threadIdx.x; i < BKT; i += P1_T)
        cnt[(size_t)i * P1_NB + blockIdx.x] = h[i];
}

// Sum the 8 degree copies -> dis = rsqrt(deg+1), dsi = sqrt(deg+1).
__global__ void reduce8_kernel(const int* __restrict__ cnt8,
                               float* __restrict__ dis, float* __restrict__ dsi) {
    int i = blockIdx.x * blockDim.x + threadIdx.x;
    if (i >= NN) return;
    int dsum = 0;
    #pragma unroll
    for (int k = 0; k < NXCD; ++k) dsum += cnt8[(size_t)k * NN + i];
    float dg = (float)(dsum + 1);          // +1 self loop, always > 0
    dis[i] = rsqrtf(dg);
    dsi[i] = sqrtf(dg);
}

// y1 = bf16( dis (x) x )   (row-broadcast scale), float4 -> 4x bf16.
__global__ void scale_kernel(const float4* __restrict__ x, const float* __restrict__ dis,
                             ushort4* __restrict__ y1) {
    int idx = blockIdx.x * blockDim.x + threadIdx.x; // over NN*16
    if (idx >= NN * (D / 4)) return;
    float s = dis[idx >> 4];
    float4 v = x[idx];
    ushort4 o;
    o.x = f2bf(s * v.x); o.y = f2bf(s * v.y); o.z = f2bf(s * v.z); o.w = f2bf(s * v.w);
    y1[idx] = o;
}

// Pass 1b: exclusive scan of cnt[SCN] in place (bucket-major order).
__global__ void __launch_bounds__(1024) p1_scan(int* __restrict__ cnt) {
    __shared__ int sums[1024];
    const int per = SCN / 1024; // 64
    int t = threadIdx.x;
    int s = 0;
    for (int i = t * per; i < (t + 1) * per; ++i) s += cnt[i];
    sums[t] = s;
    __syncthreads();
    for (int st = 1; st < 1024; st <<= 1) {
        int v = (t >= st) ? sums[t - st] : 0;
        __syncthreads();
        sums[t] += v;
        __syncthreads();
    }
    int run = sums[t] - s; // exclusive
    for (int i = t * per; i < (t + 1) * per; ++i) { int v = cnt[i]; cnt[i] = run; run += v; }
}

// Pass 1c: scatter packed (rloc<<17 | col) u32 into bucket-contiguous storage.
__global__ void __launch_bounds__(P1_T) p1_scatter(const int* __restrict__ row,
                                                   const int* __restrict__ col,
                                                   const int* __restrict__ base,
                                                   u32* __restrict__ buck) {
    __shared__ int cur[BKT];
    for (int i = threadIdx.x; i < BKT; i += P1_T)
        cur[i] = base[(size_t)i * P1_NB + blockIdx.x];
    __syncthreads();
    int beg = blockIdx.x * EPB, end = min(NE, beg + EPB);
    for (int e = beg + threadIdx.x; e < end; e += P1_T) {
        int r = row[e], c = col[e];
        int b = r / BROWS;
        int pos = atomicAdd(&cur[b], 1); // LDS atomic
        buck[pos] = ((u32)(r - b * BROWS) << 17) | (u32)c;
    }
}

// Pass 2: one block per bucket — LDS row-count, LDS scan -> rowptr, local scatter -> adjc.
__global__ void __launch_bounds__(1024) p2_build(const int* __restrict__ base,
                                                 const u32* __restrict__ buck,
                                                 int* __restrict__ adjc,
                                                 int* __restrict__ rowptr) {
    __shared__ int ca[BROWS];
    __shared__ int sums[1024];
    int b = blockIdx.x, t = threadIdx.x;
    int row0 = b * BROWS;
    int nrows = min(BROWS, NN - row0);
    int ebeg = base[(size_t)b * P1_NB];
    int eend = (b + 1 < BKT) ? base[(size_t)(b + 1) * P1_NB] : NE;

    for (int i = t; i < nrows; i += 1024) ca[i] = 0;
    __syncthreads();
    for (int e = ebeg + t; e < eend; e += 1024)
        atomicAdd(&ca[buck[e] >> 17], 1);
    __syncthreads();
    int v = (t < nrows) ? ca[t] : 0;
    sums[t] = v;
    __syncthreads();
    for (int st = 1; st < 1024; st <<= 1) {
        int u = (t >= st) ? sums[t - st] : 0;
        __syncthreads();
        sums[t] += u;
        __syncthreads();
    }
    int excl = sums[t] - v;
    if (t < nrows) {
        rowptr[row0 + t] = ebeg + excl;
        ca[t] = ebeg + excl;
    }
    if (b == 0 && t == 0) rowptr[NN] = NE;
    __syncthreads();
    for (int e = ebeg + t; e < eend; e += 1024) {
        u32 p = buck[e];
        int rloc = p >> 17;
        int c = (int)(p & 0x1FFFFu);
        int pos = atomicAdd(&ca[rloc], 1); // LDS atomic
        adjc[pos] = c;
    }
}

// ---------------- propagate kernels (gather, no atomics) ----------------
// One 64-lane wave per node; lane d = feature d.
// y buffers are bf16 (halved gather traffic); accumulation fp32.
// h = di * (y[n] + sum_c y[c]);  y_next = bf16(di^2 * acc).

__global__ void prop1_kernel(const int* __restrict__ rowptr,
                             const int* __restrict__ adjc,
                             const float* __restrict__ dis,
                             const u16* __restrict__ y1,
                             u16* __restrict__ y2) {
    int t = blockIdx.x * blockDim.x + threadIdx.x;
    int n = t >> 6, d = t & 63;
    if (n >= NN) return;
    int beg = rowptr[n], end = rowptr[n + 1];
    float acc = bf2f(y1[n * D + d]);      // self-loop term
    int j = beg;
    for (; j + 8 <= end; j += 8) {
        int c[8]; float v[8];
        #pragma unroll
        for (int u = 0; u < 8; ++u) c[u] = adjc[j + u];
        #pragma unroll
        for (int u = 0; u < 8; ++u) v[u] = bf2f(y1[c[u] * D + d]);
        #pragma unroll
        for (int u = 0; u < 8; ++u) acc += v[u];
    }
    for (; j < end; ++j) acc += bf2f(y1[adjc[j] * D + d]);
    float di = dis[n];
    y2[n * D + d] = f2bf(di * di * acc);  // dis * h1
}

// out = w0*x + w1*(dsi*y2[n]) + w2*di*(y2[n] + sum_c y2[c])
__global__ void prop2_kernel(const float* __restrict__ x,
                             const int* __restrict__ rowptr,
                             const int* __restrict__ adjc,
                             const float* __restrict__ dis,
                             const float* __restrict__ dsi,
                             const u16* __restrict__ y2,
                             const float* __restrict__ wsm,
                             float* __restrict__ out) {
    int t = blockIdx.x * blockDim.x + threadIdx.x;
    int n = t >> 6, d = t & 63;
    if (n >= NN) return;
    int beg = rowptr[n], end = rowptr[n + 1];
    float yn = bf2f(y2[n * D + d]);
    float acc = yn;                        // self-loop term
    int j = beg;
    for (; j + 8 <= end; j += 8) {
        int c[8]; float v[8];
        #pragma unroll
        for (int u = 0; u < 8; ++u) c[u] = adjc[j + u];
        #pragma unroll
        for (int u = 0; u < 8; ++u) v[u] = bf2f(y2[c[u] * D + d]);
        #pragma unroll
        for (int u = 0; u < 8; ++u) acc += v[u];
    }
    for (; j < end; ++j) acc += bf2f(y2[adjc[j] * D + d]);
    float di = dis[n];
    out[n * D + d] = wsm[0] * x[n * D + d] + wsm[1] * (dsi[n] * yn) + wsm[2] * (di * acc);
}

// ---------------- launch ----------------

extern "C" void kernel_launch(void* const* d_in, const int* in_sizes, int n_in,
                              void* d_out, int out_size, void* d_ws, size_t ws_size,
                              hipStream_t stream) {
    const float* x   = (const float*)d_in[0];
    const int*   ei  = (const int*)d_in[1];   // [2, NE]
    const float* hw  = (const float*)d_in[2]; // [3]
    float*       out = (float*)d_out;

    const int* row = ei;       // scatter destination
    const int* col = ei + NE;  // gather source

    char* ws = (char*)d_ws;
    size_t off = 0;
    auto alloc = [&](size_t bytes) { size_t p = off; off += (bytes + 255) & ~(size_t)255; return p; };
    float* wsm    = (float*)(ws + alloc(16));
    // buck (6.4 MB u32) aliases cnt8 (3.2 MB): cnt8 dead after reduce8, buck written later.
    u32*   buck   = (u32*)  (ws + alloc((size_t)NE * 4));
    int*   cnt8   = (int*)buck;
    float* dis    = (float*)(ws + alloc((size_t)NN * 4));
    float* dsi    = (float*)(ws + alloc((size_t)NN * 4));
    int*   cnt    = (int*)  (ws + alloc((size_t)SCN * 4));
    int*   adjc   = (int*)  (ws + alloc((size_t)NE * 4));
    int*   rowptr = (int*)  (ws + alloc((size_t)(NN + 1) * 4));
    u16*   y1     = (u16*)  (ws + alloc((size_t)NN * D * 2));
    u16*   y2     = (u16*)  (ws + alloc((size_t)NN * D * 2));

    hipMemsetAsync(cnt8, 0, (size_t)NXCD * NN * 4, stream);

    p1_count<<<P1_NB, P1_T, 0, stream>>>(row, col, cnt, cnt8);
    reduce8_kernel<<<(NN + 255) / 256, 256, 0, stream>>>(cnt8, dis, dsi);
    softmax_kernel<<<1, 1, 0, stream>>>(hw, wsm);
    scale_kernel<<<(NN * (D / 4) + 255) / 256, 256, 0, stream>>>((const float4*)x, dis, (ushort4*)y1);

    p1_scan   <<<1, 1024, 0, stream>>>(cnt);
    p1_scatter<<<P1_NB, P1_T, 0, stream>>>(row, col, cnt, buck);
    p2_build  <<<BKT, 1024, 0, stream>>>(cnt, buck, adjc, rowptr);

    const int prop_blocks = (NN * 64 + 255) / 256; // 25000
    prop1_kernel<<<prop_blocks, 256, 0, stream>>>(rowptr, adjc, dis, y1, y2);
    prop2_kernel<<<prop_blocks, 256, 0, stream>>>(x, rowptr, adjc, dis, dsi, y2, wsm, out);
}

// Round 8
// 213.223 us; speedup vs baseline: 3.7996x; 1.2646x over previous
//
#include <hip/hip_runtime.h>

#define NN 100000
#define NE 1600000
#define D 64
#define NXCD 8

#define BKT 128                          // row buckets
#define BROWS ((NN + BKT - 1) / BKT)     // 782 rows per bucket (fits 10 bits)
#define CAP 16384                        // slots per bucket (mean 12500, sigma 111)
#define P1_NB 512                        // pass-1 blocks
#define P1_T 512                         // pass-1 threads per block
#define EPB ((NE + P1_NB - 1) / P1_NB)   // 3125 edges per pass-1 block

typedef unsigned short u16;
typedef unsigned int u32;

// ---------------- bf16 helpers (bit-level, RNE) ----------------

__device__ __forceinline__ float bf2f(u16 u) {
    union { u32 i; float f; } x; x.i = ((u32)u) << 16; return x.f;
}
__device__ __forceinline__ u16 f2bf(float f) {
    union { float f; u32 i; } x; x.f = f;
    u32 r = x.i + 0x7FFF + ((x.i >> 16) & 1);   // round-to-nearest-even
    return (u16)(r >> 16);
}

__device__ __forceinline__ unsigned xcc_id() {
    unsigned v;
    asm volatile("s_getreg_b32 %0, hwreg(HW_REG_XCC_ID)" : "=s"(v));
    return v & (NXCD - 1);
}

__global__ void softmax_kernel(const float* __restrict__ hw, float* __restrict__ wsm) {
    float m = fmaxf(fmaxf(hw[0], hw[1]), hw[2]);
    float e0 = expf(hw[0] - m), e1 = expf(hw[1] - m), e2 = expf(hw[2] - m);
    float s = e0 + e1 + e2;
    wsm[0] = e0 / s; wsm[1] = e1 / s; wsm[2] = e2 / s;
}

// ---------------- fused pass 1: stage edges in LDS, histogram, reserve, scatter ---
// Also folds the per-XCD col-degree histogram (L2-local workgroup-scope atomics).
__global__ void __launch_bounds__(P1_T) fused_p1(const int* __restrict__ row,
                                                 const int* __restrict__ col,
                                                 int* __restrict__ cnt8,
                                                 int* __restrict__ bcnt,
                                                 u32* __restrict__ buck) {
    __shared__ int lds_r[EPB];
    __shared__ int lds_c[EPB];
    __shared__ int h[BKT];
    int t = threadIdx.x;
    unsigned k = xcc_id();
    int* degc = cnt8 + (size_t)k * NN;
    int beg = blockIdx.x * EPB, end = min(NE, beg + EPB);
    int n = end - beg;
    for (int i = t; i < BKT; i += P1_T) h[i] = 0;
    __syncthreads();
    // stage + col-degree + row-bucket histogram
    for (int i = t; i < n; i += P1_T) {
        int r = row[beg + i], c = col[beg + i];
        lds_r[i] = r; lds_c[i] = c;
        __hip_atomic_fetch_add(&degc[c], 1, __ATOMIC_RELAXED, __HIP_MEMORY_SCOPE_WORKGROUP);
        atomicAdd(&h[r / BROWS], 1);
    }
    __syncthreads();
    // reserve space in each bucket
    for (int b = t; b < BKT; b += P1_T) {
        int cl = h[b];
        h[b] = atomicAdd(&bcnt[b], cl);   // h[b] now = this block's base cursor
    }
    __syncthreads();
    // scatter packed (rloc<<17 | col)
    for (int i = t; i < n; i += P1_T) {
        int r = lds_r[i], c = lds_c[i];
        int b = r / BROWS;
        int pos = atomicAdd(&h[b], 1);    // LDS atomic
        buck[(size_t)b * CAP + pos] = ((u32)(r - b * BROWS) << 17) | (u32)c;
    }
}

// Sum the 8 degree copies -> dis = rsqrt(deg+1), dsi = sqrt(deg+1).
__global__ void reduce8_kernel(const int* __restrict__ cnt8,
                               float* __restrict__ dis, float* __restrict__ dsi) {
    int i = blockIdx.x * blockDim.x + threadIdx.x;
    if (i >= NN) return;
    int dsum = 0;
    #pragma unroll
    for (int k = 0; k < NXCD; ++k) dsum += cnt8[(size_t)k * NN + i];
    float dg = (float)(dsum + 1);          // +1 self loop, always > 0
    dis[i] = rsqrtf(dg);
    dsi[i] = sqrtf(dg);
}

// y1 = bf16( dis (x) x )
__global__ void scale_kernel(const float4* __restrict__ x, const float* __restrict__ dis,
                             ushort4* __restrict__ y1) {
    int idx = blockIdx.x * blockDim.x + threadIdx.x; // over NN*16
    if (idx >= NN * (D / 4)) return;
    float s = dis[idx >> 4];
    float4 v = x[idx];
    ushort4 o;
    o.x = f2bf(s * v.x); o.y = f2bf(s * v.y); o.z = f2bf(s * v.z); o.w = f2bf(s * v.w);
    y1[idx] = o;
}

// Exclusive scan of the 128 bucket counts.
__global__ void bscan_kernel(const int* __restrict__ bcnt, int* __restrict__ scanb) {
    __shared__ int s[BKT];
    int t = threadIdx.x;
    int v = bcnt[t];
    s[t] = v;
    __syncthreads();
    for (int st = 1; st < BKT; st <<= 1) {
        int u = (t >= st) ? s[t - st] : 0;
        __syncthreads();
        s[t] += u;
        __syncthreads();
    }
    scanb[t] = s[t] - v;
    if (t == BKT - 1) scanb[BKT] = s[t];
}

// Pass 2: one block per bucket — LDS row-count, LDS scan -> rowptr, local scatter -> adjc.
__global__ void __launch_bounds__(1024) p2_build(const int* __restrict__ scanb,
                                                 const u32* __restrict__ buck,
                                                 int* __restrict__ adjc,
                                                 int* __restrict__ rowptr) {
    __shared__ int ca[BROWS];
    __shared__ int sums[1024];
    int b = blockIdx.x, t = threadIdx.x;
    int row0 = b * BROWS;
    int nrows = min(BROWS, NN - row0);
    int ebeg = scanb[b];
    int cntb = scanb[b + 1] - ebeg;
    const u32* eb = buck + (size_t)b * CAP;

    for (int i = t; i < nrows; i += 1024) ca[i] = 0;
    __syncthreads();
    for (int e = t; e < cntb; e += 1024)
        atomicAdd(&ca[eb[e] >> 17], 1);
    __syncthreads();
    int v = (t < nrows) ? ca[t] : 0;
    sums[t] = v;
    __syncthreads();
    for (int st = 1; st < 1024; st <<= 1) {
        int u = (t >= st) ? sums[t - st] : 0;
        __syncthreads();
        sums[t] += u;
        __syncthreads();
    }
    int excl = sums[t] - v;
    if (t < nrows) {
        rowptr[row0 + t] = ebeg + excl;
        ca[t] = ebeg + excl;
    }
    if (b == 0 && t == 0) rowptr[NN] = NE;
    __syncthreads();
    for (int e = t; e < cntb; e += 1024) {
        u32 p = eb[e];
        int pos = atomicAdd(&ca[p >> 17], 1); // LDS atomic
        adjc[pos] = (int)(p & 0x1FFFFu);
    }
}

// ---------------- propagate kernels (gather, no atomics) ----------------
// One wave per node. 4 subgroups of 16 lanes: subgroup sg handles edge slot sg,
// lane covers feature quad fq = (l&15): features fq*4..fq*4+3 as ushort4 (8B).
// 16 edges (16 line requests) in flight per batch. fp32 accum, shfl-reduce.

__global__ void prop1_kernel(const int* __restrict__ rowptr,
                             const int* __restrict__ adjc,
                             const float* __restrict__ dis,
                             const u16* __restrict__ y1,
                             u16* __restrict__ y2) {
    int t = blockIdx.x * blockDim.x + threadIdx.x;
    int n = t >> 6, l = t & 63;
    if (n >= NN) return;
    int sg = l >> 4, fq = l & 15;
    int beg = rowptr[n], end = rowptr[n + 1];
    float a0 = 0.f, a1 = 0.f, a2 = 0.f, a3 = 0.f;
    int j = beg;
    for (; j + 16 <= end; j += 16) {
        #pragma unroll
        for (int u = 0; u < 4; ++u) {
            int c = adjc[j + u * 4 + sg];
            ushort4 v = *(const ushort4*)&y1[c * D + fq * 4];
            a0 += bf2f(v.x); a1 += bf2f(v.y); a2 += bf2f(v.z); a3 += bf2f(v.w);
        }
    }
    for (; j + 4 <= end; j += 4) {
        int c = adjc[j + sg];
        ushort4 v = *(const ushort4*)&y1[c * D + fq * 4];
        a0 += bf2f(v.x); a1 += bf2f(v.y); a2 += bf2f(v.z); a3 += bf2f(v.w);
    }
    if (sg < end - j) {
        int c = adjc[j + sg];
        ushort4 v = *(const ushort4*)&y1[c * D + fq * 4];
        a0 += bf2f(v.x); a1 += bf2f(v.y); a2 += bf2f(v.z); a3 += bf2f(v.w);
    }
    // reduce across the 4 subgroups (lanes l, l^16, l^32, l^48)
    a0 += __shfl_xor(a0, 16); a0 += __shfl_xor(a0, 32);
    a1 += __shfl_xor(a1, 16); a1 += __shfl_xor(a1, 32);
    a2 += __shfl_xor(a2, 16); a2 += __shfl_xor(a2, 32);
    a3 += __shfl_xor(a3, 16); a3 += __shfl_xor(a3, 32);
    if (l < 16) {
        ushort4 s = *(const ushort4*)&y1[n * D + l * 4];   // self loop
        a0 += bf2f(s.x); a1 += bf2f(s.y); a2 += bf2f(s.z); a3 += bf2f(s.w);
        float di = dis[n], d2 = di * di;
        ushort4 o;
        o.x = f2bf(d2 * a0); o.y = f2bf(d2 * a1); o.z = f2bf(d2 * a2); o.w = f2bf(d2 * a3);
        *(ushort4*)&y2[n * D + l * 4] = o;
    }
}

// out = w0*x + w1*(dsi*y2[n]) + w2*di*(y2[n] + sum_c y2[c])
__global__ void prop2_kernel(const float* __restrict__ x,
                             const int* __restrict__ rowptr,
                             const int* __restrict__ adjc,
                             const float* __restrict__ dis,
                             const float* __restrict__ dsi,
                             const u16* __restrict__ y2,
                             const float* __restrict__ wsm,
                             float* __restrict__ out) {
    int t = blockIdx.x * blockDim.x + threadIdx.x;
    int n = t >> 6, l = t & 63;
    if (n >= NN) return;
    int sg = l >> 4, fq = l & 15;
    int beg = rowptr[n], end = rowptr[n + 1];
    float a0 = 0.f, a1 = 0.f, a2 = 0.f, a3 = 0.f;
    int j = beg;
    for (; j + 16 <= end; j += 16) {
        #pragma unroll
        for (int u = 0; u < 4; ++u) {
            int c = adjc[j + u * 4 + sg];
            ushort4 v = *(const ushort4*)&y2[c * D + fq * 4];
            a0 += bf2f(v.x); a1 += bf2f(v.y); a2 += bf2f(v.z); a3 += bf2f(v.w);
        }
    }
    for (; j + 4 <= end; j += 4) {
        int c = adjc[j + sg];
        ushort4 v = *(const ushort4*)&y2[c * D + fq * 4];
        a0 += bf2f(v.x); a1 += bf2f(v.y); a2 += bf2f(v.z); a3 += bf2f(v.w);
    }
    if (sg < end - j) {
        int c = adjc[j + sg];
        ushort4 v = *(const ushort4*)&y2[c * D + fq * 4];
        a0 += bf2f(v.x); a1 += bf2f(v.y); a2 += bf2f(v.z); a3 += bf2f(v.w);
    }
    a0 += __shfl_xor(a0, 16); a0 += __shfl_xor(a0, 32);
    a1 += __shfl_xor(a1, 16); a1 += __shfl_xor(a1, 32);
    a2 += __shfl_xor(a2, 16); a2 += __shfl_xor(a2, 32);
    a3 += __shfl_xor(a3, 16); a3 += __shfl_xor(a3, 32);
    if (l < 16) {
        ushort4 s = *(const ushort4*)&y2[n * D + l * 4];
        float y0 = bf2f(s.x), y1v = bf2f(s.y), y2v = bf2f(s.z), y3 = bf2f(s.w);
        a0 += y0; a1 += y1v; a2 += y2v; a3 += y3;   // self loop in hop-2 sum
        float di = dis[n], ds = dsi[n];
        float w0 = wsm[0], w1 = wsm[1], w2 = wsm[2];
        float4 xv = *(const float4*)&x[n * D + l * 4];
        float4 o;
        o.x = w0 * xv.x + w1 * (ds * y0) + w2 * (di * a0);
        o.y = w0 * xv.y + w1 * (ds * y1v) + w2 * (di * a1);
        o.z = w0 * xv.z + w1 * (ds * y2v) + w2 * (di * a2);
        o.w = w0 * xv.w + w1 * (ds * y3) + w2 * (di * a3);
        *(float4*)&out[n * D + l * 4] = o;
    }
}

// ---------------- launch ----------------

extern "C" void kernel_launch(void* const* d_in, const int* in_sizes, int n_in,
                              void* d_out, int out_size, void* d_ws, size_t ws_size,
                              hipStream_t stream) {
    const float* x   = (const float*)d_in[0];
    const int*   ei  = (const int*)d_in[1];   // [2, NE]
    const float* hw  = (const float*)d_in[2]; // [3]
    float*       out = (float*)d_out;

    const int* row = ei;       // scatter destination
    const int* col = ei + NE;  // gather source

    char* ws = (char*)d_ws;
    size_t off = 0;
    auto alloc = [&](size_t bytes) { size_t p = off; off += (bytes + 255) & ~(size_t)255; return p; };
    float* wsm    = (float*)(ws + alloc(16));
    int*   cnt8   = (int*)  (ws + alloc((size_t)NXCD * NN * 4));
    int*   bcnt   = (int*)  (ws + alloc((size_t)BKT * 4));
    int*   scanb  = (int*)  (ws + alloc((size_t)(BKT + 1) * 4));
    float* dis    = (float*)(ws + alloc((size_t)NN * 4));
    float* dsi    = (float*)(ws + alloc((size_t)NN * 4));
    u32*   buck   = (u32*)  (ws + alloc((size_t)BKT * CAP * 4));
    int*   adjc   = (int*)  (ws + alloc((size_t)NE * 4));
    int*   rowptr = (int*)  (ws + alloc((size_t)(NN + 1) * 4));
    u16*   y1     = (u16*)  (ws + alloc((size_t)NN * D * 2));
    u16*   y2     = (u16*)  (ws + alloc((size_t)NN * D * 2));

    hipMemsetAsync(cnt8, 0, (size_t)NXCD * NN * 4, stream);
    hipMemsetAsync(bcnt, 0, (size_t)BKT * 4, stream);

    fused_p1<<<P1_NB, P1_T, 0, stream>>>(row, col, cnt8, bcnt, buck);
    reduce8_kernel<<<(NN + 255) / 256, 256, 0, stream>>>(cnt8, dis, dsi);
    softmax_kernel<<<1, 1, 0, stream>>>(hw, wsm);
    scale_kernel<<<(NN * (D / 4) + 255) / 256, 256, 0, stream>>>((const float4*)x, dis, (ushort4*)y1);
    bscan_kernel<<<1, BKT, 0, stream>>>(bcnt, scanb);
    p2_build<<<BKT, 1024, 0, stream>>>(scanb, buck, adjc, rowptr);

    const int prop_blocks = (NN * 64 + 255) / 256; // 25000
    prop1_kernel<<<prop_blocks, 256, 0, stream>>>(rowptr, adjc, dis, y1, y2);
    prop2_kernel<<<prop_blocks, 256, 0, stream>>>(x, rowptr, adjc, dis, dsi, y2, wsm, out);
}